// Round 3
// baseline (3135.052 us; speedup 1.0000x reference)
//
#include <hip/hip_runtime.h>
#include <stdint.h>

#define TT 128
#define BB 128
#define NN 1024

// World model (verified bit-exact in R9):
//   tx: packed bf16 storage (runtime-probed each launch; probe also handles f32),
//   W : f32 storage, bf16-rounded values; b: f32; out: f32.
//   Reference recurrent sum: OpenBLAS sgemm kc=384 panels, sequential-k
//   single accumulator per panel, a = (P0 + P1) + P2.  With binary y all
//   products are exact, so this association is reproduced exactly.
//
// R12: R11 (split each sample across 2 blocks -> all 256 CUs, halving the
// compulsory per-CU gather traffic) with the cross-block exchange redone
// using textbook agent-scope acquire/release:
//   - masks: relaxed __hip_atomic_store at AGENT scope
//   - __syncthreads() ; thread0: __threadfence() + RELEASE flag store
//   - partner: ACQUIRE flag spin (plain atomic loads, no RMW), then
//     relaxed mask loads
//   - mask slots mod-4 (reuse distance 4 steps, 64KB)
//   - host-side ws_size guard: fall back to the verified R10 single-block
//     kernel if the workspace cannot hold masks+flags.

typedef unsigned short ushort8 __attribute__((ext_vector_type(8)));

__device__ __forceinline__ float bfbits2f(uint32_t lo16) {
  union { uint32_t i; float f; } c;
  c.i = lo16 << 16;
  return c.f;
}

// ---------------------------------------------------------------------------
// Kernel 0: in-place f32 transpose of W (tile-pair swap)  +  bf16 repack of
// W^T into ws  +  losslessness check (dirty flag set if any f32 word has
// nonzero low 16 bits — then the gather kernels use the f32 path).
// ---------------------------------------------------------------------------
__global__ __launch_bounds__(256) void w_transpose_repack(
    float* __restrict__ W, uint16_t* __restrict__ WtBf,
    uint32_t* __restrict__ dirty) {
  __shared__ float ta[32][33];
  __shared__ float tb[32][33];

  int rem = blockIdx.x;
  int I = 0;
  while (rem >= (32 - I)) { rem -= (32 - I); ++I; }
  const int J = I + rem;

  const int lx = threadIdx.x & 31;
  const int ly = threadIdx.x >> 5;  // 0..7
  uint32_t bad = 0;

  if (I == J) {
#pragma unroll
    for (int i = 0; i < 4; ++i)
      ta[ly + i * 8][lx] = W[(I * 32 + ly + i * 8) * NN + J * 32 + lx];
    __syncthreads();
#pragma unroll
    for (int i = 0; i < 4; ++i) {
      const int idx = (I * 32 + ly + i * 8) * NN + J * 32 + lx;
      const float v = ta[lx][ly + i * 8];
      const uint32_t bits = __float_as_uint(v);
      W[idx] = v;
      WtBf[idx] = (uint16_t)(bits >> 16);
      bad |= (bits & 0xFFFFu);
    }
  } else {
#pragma unroll
    for (int i = 0; i < 4; ++i) {
      ta[ly + i * 8][lx] = W[(I * 32 + ly + i * 8) * NN + J * 32 + lx];
      tb[ly + i * 8][lx] = W[(J * 32 + ly + i * 8) * NN + I * 32 + lx];
    }
    __syncthreads();
#pragma unroll
    for (int i = 0; i < 4; ++i) {
      const int idxA = (J * 32 + ly + i * 8) * NN + I * 32 + lx;
      const float va = ta[lx][ly + i * 8];
      const uint32_t bitsA = __float_as_uint(va);
      W[idxA] = va;
      WtBf[idxA] = (uint16_t)(bitsA >> 16);
      bad |= (bitsA & 0xFFFFu);

      const int idxB = (I * 32 + ly + i * 8) * NN + J * 32 + lx;
      const float vb = tb[lx][ly + i * 8];
      const uint32_t bitsB = __float_as_uint(vb);
      W[idxB] = vb;
      WtBf[idxB] = (uint16_t)(bitsB >> 16);
      bad |= (bitsB & 0xFFFFu);
    }
  }
  const unsigned long long bm = __ballot(bad != 0);
  if ((threadIdx.x & 63) == 0 && bm) atomicOr(dirty, 1u);
}

// ---------------------------------------------------------------------------
// Kernel 1a (primary): per-HALF-sample LIF. 256 blocks x 512 threads; block
// bb handles sample b = bb&127, neuron half h = bb>>7. Partner bb^128 (same
// XCD under round-robin). Per step: local ballot (8 u64 chunks), agent-scope
// release/acquire mask exchange, full 1024-entry active list rebuilt locally,
// then the verified 32-wide sentinel-padded gather, sequential f32 adds in
// ascending k (exact reference association).
// ---------------------------------------------------------------------------
__global__ __launch_bounds__(512) void lif_half(
    const void* __restrict__ tx_raw, const float* __restrict__ bias,
    const float* __restrict__ WtF32, const uint16_t* __restrict__ WtBf,
    const uint32_t* __restrict__ dirty,
    unsigned long long* __restrict__ gmask, unsigned int* __restrict__ gflag,
    float* __restrict__ out) {
  const int bb = blockIdx.x;
  const int b = bb & 127;         // sample
  const int h = bb >> 7;          // neuron half
  const int pp = bb ^ 128;        // partner block (other half, same XCD)
  const int tid = threadIdx.x;    // 0..511
  const int lane = tid & 63;
  const int wv = tid >> 6;        // 0..7
  const int n = (h << 9) + tid;   // global neuron index == recurrent index k

  __shared__ uint16_t lst[NN] __attribute__((aligned(16)));
  __shared__ unsigned long long smask[16];  // chunk j covers k in [j*64,(j+1)*64)
  __shared__ int sprobe;

  // ---- runtime tx-storage probe (bf16-packed vs f32), as verified in R9 ----
  if (tid == 0) sprobe = 0;
  __syncthreads();
  {
    const uint32_t* txw = (const uint32_t*)tx_raw;
    int local = 0;
#pragma unroll
    for (int i = 0; i < 2; ++i) {
      const uint32_t f = (txw[tid * 2 + i] >> 7) & 0xFFu;
      local += (f >= 0x74u && f < 0x81u) ? 1 : 0;
    }
    atomicAdd(&sprobe, local);
  }
  __syncthreads();
  const bool tx_is_bf16 = (sprobe > 512);    // of 1024 sampled words
  const bool w_bf = (*dirty == 0u);          // bf16 repack lossless?

  const uint16_t* __restrict__ txh = (const uint16_t*)tx_raw;
  const float* __restrict__ txf = (const float*)tx_raw;
  const float bz = bias[n];

  const uint16_t* __restrict__ rowB = WtBf + n;
  const float* __restrict__ rowF = WtF32 + n;

  float v = 0.0f;   // membrane (REST = 0)
  int y = 0;        // previous spike

  // 32-wide gather over a sentinel-padded panel list [pbase, pbase+cnt),
  // cnt % 32 == 0. Ascending k, ONE accumulator, adds strictly in list
  // order (exact reference association; sentinel rows add +0.0f exactly).
  auto gB = [&](int pbase, int cnt) -> float {
    float acc = 0.0f;
    for (int i = 0; i < cnt; i += 32) {
      const ushort8* lp = (const ushort8*)(lst + pbase + i);
      const ushort8 a0 = lp[0];
      const ushort8 a1 = lp[1];
      const ushort8 a2 = lp[2];
      const ushort8 a3 = lp[3];
      float wbuf[32];
#pragma unroll
      for (int u = 0; u < 8; ++u) {
        const int k = __builtin_amdgcn_readfirstlane((int)a0[u]);
        wbuf[u] = bfbits2f((uint32_t)rowB[k << 10]);
      }
#pragma unroll
      for (int u = 0; u < 8; ++u) {
        const int k = __builtin_amdgcn_readfirstlane((int)a1[u]);
        wbuf[8 + u] = bfbits2f((uint32_t)rowB[k << 10]);
      }
#pragma unroll
      for (int u = 0; u < 8; ++u) {
        const int k = __builtin_amdgcn_readfirstlane((int)a2[u]);
        wbuf[16 + u] = bfbits2f((uint32_t)rowB[k << 10]);
      }
#pragma unroll
      for (int u = 0; u < 8; ++u) {
        const int k = __builtin_amdgcn_readfirstlane((int)a3[u]);
        wbuf[24 + u] = bfbits2f((uint32_t)rowB[k << 10]);
      }
#pragma unroll
      for (int u = 0; u < 32; ++u) acc += wbuf[u];
    }
    return acc;
  };

  // f32 fallback (cold path): unpadded bounds [s, e), 8-wide structure.
  auto gF = [&](int s, int e) -> float {
    float acc = 0.0f;
    int i = s;
    for (; i + 8 <= e; i += 8) {
      float w[8];
#pragma unroll
      for (int u = 0; u < 8; ++u) {
        const int k = __builtin_amdgcn_readfirstlane((int)lst[i + u]);
        w[u] = rowF[k << 10];
      }
#pragma unroll
      for (int u = 0; u < 8; ++u) acc += w[u];
    }
    for (; i < e; ++i) {
      const int k = __builtin_amdgcn_readfirstlane((int)lst[i]);
      acc += rowF[k << 10];
    }
    return acc;
  };

  for (int t = 0; t < TT; ++t) {
    const int sl = t & 3;  // mod-4 slot
    // ---- local ballot + publish own mask chunks (relaxed, agent scope) ----
    const unsigned long long m = __ballot(y);
    if (lane == 0) {
      smask[h * 8 + wv] = m;
      __hip_atomic_store(&gmask[((size_t)bb * 4 + sl) * 8 + wv], m,
                         __ATOMIC_RELAXED, __HIP_MEMORY_SCOPE_AGENT);
    }

    // issue tx load early; consumed after the gather
    const int off = (t * BB + b) * NN + n;
    float xx;
    if (tx_is_bf16)
      xx = bfbits2f((uint32_t)__builtin_nontemporal_load(&txh[off]));
    else
      xx = __builtin_nontemporal_load(&txf[off]);

    __syncthreads();  // SYNC_A: all 8 mask stores program-ordered before flag
    if (tid == 0) {
      __threadfence();  // agent-scope fence (belt + braces with release below)
      __hip_atomic_store(&gflag[bb], (unsigned int)(t + 1),
                         __ATOMIC_RELEASE, __HIP_MEMORY_SCOPE_AGENT);
    }
    if (tid < 8) {
      // acquire-spin on partner's monotonic flag (plain loads, no RMW)
      while (__hip_atomic_load(&gflag[pp], __ATOMIC_ACQUIRE,
                               __HIP_MEMORY_SCOPE_AGENT) < (unsigned int)(t + 1)) {
        __builtin_amdgcn_s_sleep(1);
      }
      smask[(1 - h) * 8 + tid] =
          __hip_atomic_load(&gmask[((size_t)pp * 4 + sl) * 8 + tid],
                            __ATOMIC_RELAXED, __HIP_MEMORY_SCOPE_AGENT);
      // Slot-reuse safety (mod-4): we rewrite slot sl at t+4 only after the
      // spins of steps t+1..t+3 observed partner flag >= t+4, which the
      // partner sets strictly after completing its step-t read of slot sl.
    }
    __syncthreads();  // SYNC_B: all 16 mask chunks in LDS

    // ---- per-thread counts/prefixes from the 16 mask chunks ----
    unsigned long long mk[16];
    int cnt[16];
#pragma unroll
    for (int i = 0; i < 16; ++i) {
      mk[i] = smask[i];
      cnt[i] = __popcll(mk[i]);
    }
    int pref[16];
    {
      int s = 0;
#pragma unroll
      for (int j = 0; j < 6; ++j) { pref[j] = s; s += cnt[j]; }
    }
    {
      int s = 384;
#pragma unroll
      for (int j = 6; j < 12; ++j) { pref[j] = s; s += cnt[j]; }
    }
    {
      int s = 768;
#pragma unroll
      for (int j = 12; j < 16; ++j) { pref[j] = s; s += cnt[j]; }
    }
    const int c0 = pref[5] + cnt[5];          // panel 0 count (k < 384)
    const int c1 = pref[11] + cnt[11] - 384;  // panel 1 count
    const int c2 = pref[15] + cnt[15] - 768;  // panel 2 count

    // ---- build full active list: wave wv materializes chunks 2wv, 2wv+1 ----
#pragma unroll
    for (int jj = 0; jj < 2; ++jj) {
      const int j = wv * 2 + jj;
      const unsigned long long bits = mk[j];
      if ((bits >> lane) & 1ull) {
        const int below = __builtin_amdgcn_mbcnt_hi(
            (uint32_t)(bits >> 32),
            __builtin_amdgcn_mbcnt_lo((uint32_t)bits, 0));
        lst[pref[j] + below] = (uint16_t)(j * 64 + lane);
      }
    }
    // sentinel padding to x32 per panel (k=NN -> zeroed row, +0.0f exact)
    if (tid < 96) {
      const int p = tid >> 5, jn = tid & 31;
      const int c = (p == 0) ? c0 : ((p == 1) ? c1 : c2);
      if (c + jn < ((c + 31) & ~31)) lst[p * 384 + c + jn] = (uint16_t)NN;
    }
    __syncthreads();  // SYNC_C: lst complete

    // ---- recurrent term: (P0 + P1) + P2, sequential k within panels ----
    float P0, P1, P2;
    if (w_bf) {
      P0 = gB(0, (c0 + 31) & ~31);
      P1 = gB(384, (c1 + 31) & ~31);
      P2 = gB(768, (c2 + 31) & ~31);
    } else {
      P0 = gF(0, c0);
      P1 = gF(384, 384 + c1);
      P2 = gF(768, 768 + c2);
    }
    const float a = (P0 + P1) + P2;

    // ---- LIF update, reference op order, f32 ----
    const float xv = (xx + a) + bz;
    v = (y ? 0.0f : 0.5f * v) + xv;
    y = (v > 0.5f);

    __builtin_nontemporal_store(y ? 1.0f : 0.0f, &out[off]);
    // No end-of-step barrier needed: lst(t+1) writes happen after
    // SYNC_B(t+1); gather(t) LDS reads complete before SYNC_A(t+1) (barrier
    // arrival drains lgkmcnt), and smask(t+1) writes are after SYNC_C(t).
  }
}

// ---------------------------------------------------------------------------
// Kernel 1b (fallback, R10-verified): per-sample LIF, 128 blocks x 1024 thr.
// Used only if ws_size cannot hold the mask/flag exchange buffers.
// ---------------------------------------------------------------------------
__global__ __launch_bounds__(1024) void lif_persample(
    const void* __restrict__ tx_raw, const float* __restrict__ bias,
    const float* __restrict__ WtF32, const uint16_t* __restrict__ WtBf,
    const uint32_t* __restrict__ dirty, float* __restrict__ out) {
  const int b = blockIdx.x;
  const int tid = threadIdx.x;
  const int lane = tid & 63;
  const int wv = tid >> 6;

  __shared__ uint16_t lst[NN] __attribute__((aligned(16)));
  __shared__ int wcnt[16];
  __shared__ int sprobe;

  if (tid == 0) sprobe = 0;
  __syncthreads();
  {
    const uint32_t* txw = (const uint32_t*)tx_raw;
    int local = 0;
#pragma unroll
    for (int i = 0; i < 2; ++i) {
      const uint32_t f = (txw[tid * 2 + i] >> 7) & 0xFFu;
      local += (f >= 0x74u && f < 0x81u) ? 1 : 0;
    }
    atomicAdd(&sprobe, local);
  }
  __syncthreads();
  const bool tx_is_bf16 = (sprobe > 1024);
  const bool w_bf = (*dirty == 0u);

  const uint16_t* __restrict__ txh = (const uint16_t*)tx_raw;
  const float* __restrict__ txf = (const float*)tx_raw;
  const float bz = bias[tid];

  const int pidx = (wv < 6) ? 0 : ((wv < 12) ? 1 : 2);
  const int pw0 = (pidx == 0) ? 0 : ((pidx == 1) ? 6 : 12);

  const uint16_t* __restrict__ rowB = WtBf + tid;
  const float* __restrict__ rowF = WtF32 + tid;

  float v = 0.0f;
  int y = 0;

  auto gB = [&](int pbase, int cnt) -> float {
    float acc = 0.0f;
    for (int i = 0; i < cnt; i += 32) {
      const ushort8* lp = (const ushort8*)(lst + pbase + i);
      const ushort8 a0 = lp[0];
      const ushort8 a1 = lp[1];
      const ushort8 a2 = lp[2];
      const ushort8 a3 = lp[3];
      float wbuf[32];
#pragma unroll
      for (int u = 0; u < 8; ++u) {
        const int k = __builtin_amdgcn_readfirstlane((int)a0[u]);
        wbuf[u] = bfbits2f((uint32_t)rowB[k << 10]);
      }
#pragma unroll
      for (int u = 0; u < 8; ++u) {
        const int k = __builtin_amdgcn_readfirstlane((int)a1[u]);
        wbuf[8 + u] = bfbits2f((uint32_t)rowB[k << 10]);
      }
#pragma unroll
      for (int u = 0; u < 8; ++u) {
        const int k = __builtin_amdgcn_readfirstlane((int)a2[u]);
        wbuf[16 + u] = bfbits2f((uint32_t)rowB[k << 10]);
      }
#pragma unroll
      for (int u = 0; u < 8; ++u) {
        const int k = __builtin_amdgcn_readfirstlane((int)a3[u]);
        wbuf[24 + u] = bfbits2f((uint32_t)rowB[k << 10]);
      }
#pragma unroll
      for (int u = 0; u < 32; ++u) acc += wbuf[u];
    }
    return acc;
  };

  auto gF = [&](int s, int e) -> float {
    float acc = 0.0f;
    int i = s;
    for (; i + 8 <= e; i += 8) {
      float w[8];
#pragma unroll
      for (int u = 0; u < 8; ++u) {
        const int k = __builtin_amdgcn_readfirstlane((int)lst[i + u]);
        w[u] = rowF[k << 10];
      }
#pragma unroll
      for (int u = 0; u < 8; ++u) acc += w[u];
    }
    for (; i < e; ++i) {
      const int k = __builtin_amdgcn_readfirstlane((int)lst[i]);
      acc += rowF[k << 10];
    }
    return acc;
  };

  for (int t = 0; t < TT; ++t) {
    const unsigned long long m = __ballot(y);
    if (lane == 0) wcnt[wv] = __popcll(m);
    __syncthreads();
    int base = 0, c0 = 0, c1 = 0, c2 = 0;
#pragma unroll
    for (int w = 0; w < 16; ++w) {
      const int c = wcnt[w];
      c0 += (w < 6) ? c : 0;
      c1 += (w >= 6 && w < 12) ? c : 0;
      c2 += (w >= 12) ? c : 0;
      base += (w >= pw0 && w < wv) ? c : 0;
    }
    if (y) {
      const int below = __builtin_amdgcn_mbcnt_hi(
          (uint32_t)(m >> 32), __builtin_amdgcn_mbcnt_lo((uint32_t)m, 0));
      lst[pidx * 384 + base + below] = (uint16_t)tid;
    }
    if (tid < 96) {
      const int p = tid >> 5, jn = tid & 31;
      const int c = (p == 0) ? c0 : ((p == 1) ? c1 : c2);
      if (c + jn < ((c + 31) & ~31)) lst[p * 384 + c + jn] = (uint16_t)NN;
    }
    __syncthreads();

    float P0, P1, P2;
    if (w_bf) {
      P0 = gB(0, (c0 + 31) & ~31);
      P1 = gB(384, (c1 + 31) & ~31);
      P2 = gB(768, (c2 + 31) & ~31);
    } else {
      P0 = gF(0, c0);
      P1 = gF(384, 384 + c1);
      P2 = gF(768, 768 + c2);
    }
    const float a = (P0 + P1) + P2;

    const int off = (t * BB + b) * NN + tid;
    const float xx = tx_is_bf16
        ? bfbits2f((uint32_t)__builtin_nontemporal_load(&txh[off]))
        : __builtin_nontemporal_load(&txf[off]);
    const float xv = (xx + a) + bz;
    v = (y ? 0.0f : 0.5f * v) + xv;
    y = (v > 0.5f);

    __builtin_nontemporal_store(y ? 1.0f : 0.0f, &out[off]);
  }
}

extern "C" void kernel_launch(void* const* d_in, const int* in_sizes, int n_in,
                              void* d_out, int out_size, void* d_ws, size_t ws_size,
                              hipStream_t stream) {
  // Inputs by element count: tx = 128*128*1024 (bf16-packed),
  // W = 1024*1024 (f32, bf16-valued), b = 1024 (f32).
  const void* tx = nullptr;
  float* W = nullptr;
  const float* bs = nullptr;
  for (int i = 0; i < n_in; ++i) {
    if (in_sizes[i] == TT * BB * NN) tx = d_in[i];
    else if (in_sizes[i] == NN * NN) W = (float*)d_in[i];
    else if (in_sizes[i] == NN) bs = (const float*)d_in[i];
  }
  float* out = (float*)d_out;                     // [T, B, N] f32 spikes

  // Workspace layout:
  //   [0, 2MB)                bf16 W^T (1024 rows)
  //   [2MB, 2MB+2KB)          zero row (sentinel k=1024)
  //   @2MB+2048               dirty flag (u32)
  //   @2MB+4096               gmask: u64[256 blocks][4 slots][8 waves] = 64KB
  //   @2MB+4096+65536         gflag: u32[256] = 1KB
  const size_t MB2 = 2u * 1024u * 1024u;
  uint16_t* WtBf = (uint16_t*)d_ws;
  uint16_t* zrow = WtBf + NN * NN;                // row index 1024
  uint32_t* dirty = (uint32_t*)((char*)d_ws + MB2 + 2048u);
  unsigned long long* gmask =
      (unsigned long long*)((char*)d_ws + MB2 + 4096u);
  unsigned int* gflag =
      (unsigned int*)((char*)d_ws + MB2 + 4096u + 65536u);
  const size_t need = MB2 + 4096u + 65536u + 1024u;

  // ws is poisoned 0xAA each launch — clear dirty flag, sentinel row, flags.
  hipMemsetAsync(dirty, 0, sizeof(uint32_t), stream);
  hipMemsetAsync(zrow, 0, NN * sizeof(uint16_t), stream);

  w_transpose_repack<<<dim3(528), dim3(256), 0, stream>>>(W, WtBf, dirty);

  if (ws_size >= need) {
    hipMemsetAsync(gflag, 0, 256 * sizeof(unsigned int), stream);
    lif_half<<<dim3(256), dim3(512), 0, stream>>>(tx, bs, W, WtBf, dirty,
                                                  gmask, gflag, out);
  } else {
    lif_persample<<<dim3(BB), dim3(1024), 0, stream>>>(tx, bs, W, WtBf, dirty,
                                                       out);
  }
}

// Round 4
// 1720.258 us; speedup vs baseline: 1.8224x; 1.8224x over previous
//
#include <hip/hip_runtime.h>
#include <stdint.h>

#define TT 128
#define BB 128
#define NN 1024

// World model (verified bit-exact in R9):
//   tx: packed bf16 storage (runtime-probed each launch; probe also handles f32),
//   W : f32 storage, bf16-rounded values; b: f32; out: f32.
//   Reference recurrent sum: OpenBLAS sgemm kc=384 panels, sequential-k
//   single accumulator per panel, a = (P0 + P1) + P2.  With binary y all
//   products are exact, so this association is reproduced exactly.
//
// R13: split-sample (2 blocks/sample -> all 256 CUs, halved per-CU gather
// traffic) with FENCELESS mask exchange. R12 proved the protocol correct but
// its acquire/release fences writeback+invalidate the XCD L2 every step
// (counters: WRITE +9MB, FETCH +17MB, dur 1855->3079 vs single-block).
// R13 packs (tag<<32 | mask_word) into single 64-bit cells stored/loaded
// with RELAXED agent-scope atomics: tag+payload arrive atomically, so no
// fences are needed; no cache writeback/invalidate is emitted.
//   - 16 cells (8 waves x 2 words) per block per step, slots mod 4
//   - slot-reuse safety: writer reaches step t+4 only after partner
//     published t+3, which is after partner's step-t read of that slot
//   - cells memset to 0 each launch (tags 1..128 never alias stale/poison)
//   - ws_size guard: falls back to verified R10 single-block kernel.

typedef unsigned short ushort8 __attribute__((ext_vector_type(8)));

__device__ __forceinline__ float bfbits2f(uint32_t lo16) {
  union { uint32_t i; float f; } c;
  c.i = lo16 << 16;
  return c.f;
}

// ---------------------------------------------------------------------------
// Kernel 0: in-place f32 transpose of W (tile-pair swap)  +  bf16 repack of
// W^T into ws  +  losslessness check (dirty flag set if any f32 word has
// nonzero low 16 bits — then the gather kernels use the f32 path).
// ---------------------------------------------------------------------------
__global__ __launch_bounds__(256) void w_transpose_repack(
    float* __restrict__ W, uint16_t* __restrict__ WtBf,
    uint32_t* __restrict__ dirty) {
  __shared__ float ta[32][33];
  __shared__ float tb[32][33];

  int rem = blockIdx.x;
  int I = 0;
  while (rem >= (32 - I)) { rem -= (32 - I); ++I; }
  const int J = I + rem;

  const int lx = threadIdx.x & 31;
  const int ly = threadIdx.x >> 5;  // 0..7
  uint32_t bad = 0;

  if (I == J) {
#pragma unroll
    for (int i = 0; i < 4; ++i)
      ta[ly + i * 8][lx] = W[(I * 32 + ly + i * 8) * NN + J * 32 + lx];
    __syncthreads();
#pragma unroll
    for (int i = 0; i < 4; ++i) {
      const int idx = (I * 32 + ly + i * 8) * NN + J * 32 + lx;
      const float v = ta[lx][ly + i * 8];
      const uint32_t bits = __float_as_uint(v);
      W[idx] = v;
      WtBf[idx] = (uint16_t)(bits >> 16);
      bad |= (bits & 0xFFFFu);
    }
  } else {
#pragma unroll
    for (int i = 0; i < 4; ++i) {
      ta[ly + i * 8][lx] = W[(I * 32 + ly + i * 8) * NN + J * 32 + lx];
      tb[ly + i * 8][lx] = W[(J * 32 + ly + i * 8) * NN + I * 32 + lx];
    }
    __syncthreads();
#pragma unroll
    for (int i = 0; i < 4; ++i) {
      const int idxA = (J * 32 + ly + i * 8) * NN + I * 32 + lx;
      const float va = ta[lx][ly + i * 8];
      const uint32_t bitsA = __float_as_uint(va);
      W[idxA] = va;
      WtBf[idxA] = (uint16_t)(bitsA >> 16);
      bad |= (bitsA & 0xFFFFu);

      const int idxB = (I * 32 + ly + i * 8) * NN + J * 32 + lx;
      const float vb = tb[lx][ly + i * 8];
      const uint32_t bitsB = __float_as_uint(vb);
      W[idxB] = vb;
      WtBf[idxB] = (uint16_t)(bitsB >> 16);
      bad |= (bitsB & 0xFFFFu);
    }
  }
  const unsigned long long bm = __ballot(bad != 0);
  if ((threadIdx.x & 63) == 0 && bm) atomicOr(dirty, 1u);
}

// ---------------------------------------------------------------------------
// Kernel 1a (primary): per-HALF-sample LIF. 256 blocks x 512 threads; block
// bb handles sample b = bb&127, neuron half h = bb>>7. Partner bb^128.
// Per step: local ballot (8 u64 chunks), tagged-cell fenceless exchange,
// full 1024-entry active list rebuilt locally, then the verified 32-wide
// sentinel-padded gather, sequential f32 adds in ascending k.
// ---------------------------------------------------------------------------
__global__ __launch_bounds__(512) void lif_half(
    const void* __restrict__ tx_raw, const float* __restrict__ bias,
    const float* __restrict__ WtF32, const uint16_t* __restrict__ WtBf,
    const uint32_t* __restrict__ dirty,
    unsigned long long* __restrict__ gmask, float* __restrict__ out) {
  const int bb = blockIdx.x;
  const int b = bb & 127;         // sample
  const int h = bb >> 7;          // neuron half
  const int pp = bb ^ 128;        // partner block (other half)
  const int tid = threadIdx.x;    // 0..511
  const int lane = tid & 63;
  const int wv = tid >> 6;        // 0..7
  const int n = (h << 9) + tid;   // global neuron index == recurrent index k

  __shared__ uint16_t lst[NN] __attribute__((aligned(16)));
  __shared__ unsigned long long smask[16];  // chunk j covers k in [j*64,(j+1)*64)
  __shared__ int sprobe;

  // ---- runtime tx-storage probe (bf16-packed vs f32), as verified in R9 ----
  if (tid == 0) sprobe = 0;
  __syncthreads();
  {
    const uint32_t* txw = (const uint32_t*)tx_raw;
    int local = 0;
#pragma unroll
    for (int i = 0; i < 2; ++i) {
      const uint32_t f = (txw[tid * 2 + i] >> 7) & 0xFFu;
      local += (f >= 0x74u && f < 0x81u) ? 1 : 0;
    }
    atomicAdd(&sprobe, local);
  }
  __syncthreads();
  const bool tx_is_bf16 = (sprobe > 512);    // of 1024 sampled words
  const bool w_bf = (*dirty == 0u);          // bf16 repack lossless?

  const uint16_t* __restrict__ txh = (const uint16_t*)tx_raw;
  const float* __restrict__ txf = (const float*)tx_raw;
  const float bz = bias[n];

  const uint16_t* __restrict__ rowB = WtBf + n;
  const float* __restrict__ rowF = WtF32 + n;

  float v = 0.0f;   // membrane (REST = 0)
  int y = 0;        // previous spike

  // 32-wide gather over a sentinel-padded panel list [pbase, pbase+cnt),
  // cnt % 32 == 0. Ascending k, ONE accumulator, adds strictly in list
  // order (exact reference association; sentinel rows add +0.0f exactly).
  auto gB = [&](int pbase, int cnt) -> float {
    float acc = 0.0f;
    for (int i = 0; i < cnt; i += 32) {
      const ushort8* lp = (const ushort8*)(lst + pbase + i);
      const ushort8 a0 = lp[0];
      const ushort8 a1 = lp[1];
      const ushort8 a2 = lp[2];
      const ushort8 a3 = lp[3];
      float wbuf[32];
#pragma unroll
      for (int u = 0; u < 8; ++u) {
        const int k = __builtin_amdgcn_readfirstlane((int)a0[u]);
        wbuf[u] = bfbits2f((uint32_t)rowB[k << 10]);
      }
#pragma unroll
      for (int u = 0; u < 8; ++u) {
        const int k = __builtin_amdgcn_readfirstlane((int)a1[u]);
        wbuf[8 + u] = bfbits2f((uint32_t)rowB[k << 10]);
      }
#pragma unroll
      for (int u = 0; u < 8; ++u) {
        const int k = __builtin_amdgcn_readfirstlane((int)a2[u]);
        wbuf[16 + u] = bfbits2f((uint32_t)rowB[k << 10]);
      }
#pragma unroll
      for (int u = 0; u < 8; ++u) {
        const int k = __builtin_amdgcn_readfirstlane((int)a3[u]);
        wbuf[24 + u] = bfbits2f((uint32_t)rowB[k << 10]);
      }
#pragma unroll
      for (int u = 0; u < 32; ++u) acc += wbuf[u];
    }
    return acc;
  };

  // f32 fallback (cold path): unpadded bounds [s, e), 8-wide structure.
  auto gF = [&](int s, int e) -> float {
    float acc = 0.0f;
    int i = s;
    for (; i + 8 <= e; i += 8) {
      float w[8];
#pragma unroll
      for (int u = 0; u < 8; ++u) {
        const int k = __builtin_amdgcn_readfirstlane((int)lst[i + u]);
        w[u] = rowF[k << 10];
      }
#pragma unroll
      for (int u = 0; u < 8; ++u) acc += w[u];
    }
    for (; i < e; ++i) {
      const int k = __builtin_amdgcn_readfirstlane((int)lst[i]);
      acc += rowF[k << 10];
    }
    return acc;
  };

  for (int t = 0; t < TT; ++t) {
    const int sl = t & 3;  // mod-4 slot
    // ---- local ballot + publish tagged cells (relaxed, fenceless) ----
    const unsigned long long m = __ballot(y);
    if (lane == 0) smask[h * 8 + wv] = m;
    if (lane < 2) {
      const uint32_t word = (lane == 0) ? (uint32_t)m : (uint32_t)(m >> 32);
      const unsigned long long cell =
          ((unsigned long long)(t + 1) << 32) | (unsigned long long)word;
      __hip_atomic_store(&gmask[((size_t)bb * 4 + sl) * 16 + wv * 2 + lane],
                         cell, __ATOMIC_RELAXED, __HIP_MEMORY_SCOPE_AGENT);
    }

    // issue tx load early; consumed after the gather
    const int off = (t * BB + b) * NN + n;
    float xx;
    if (tx_is_bf16)
      xx = bfbits2f((uint32_t)__builtin_nontemporal_load(&txh[off]));
    else
      xx = __builtin_nontemporal_load(&txf[off]);

    __syncthreads();  // SYNC_A: own smask half visible; gather(t-1) done
    if (tid < 16) {
      // spin on partner's tagged cell; tag==t+1 guarantees payload is the
      // step-t word (single-cell atomicity; no fences required)
      const size_t ci = ((size_t)pp * 4 + sl) * 16 + tid;
      unsigned long long cell;
      while (((cell = __hip_atomic_load(&gmask[ci], __ATOMIC_RELAXED,
                                        __HIP_MEMORY_SCOPE_AGENT)) >>
              32) != (unsigned long long)(t + 1)) {
        __builtin_amdgcn_s_sleep(1);
      }
      ((uint32_t*)smask)[(1 - h) * 16 + tid] = (uint32_t)cell;
    }
    __syncthreads();  // SYNC_B: all 16 mask chunks in LDS

    // ---- per-thread counts/prefixes from the 16 mask chunks ----
    unsigned long long mk[16];
    int cnt[16];
#pragma unroll
    for (int i = 0; i < 16; ++i) {
      mk[i] = smask[i];
      cnt[i] = __popcll(mk[i]);
    }
    int pref[16];
    {
      int s = 0;
#pragma unroll
      for (int j = 0; j < 6; ++j) { pref[j] = s; s += cnt[j]; }
    }
    {
      int s = 384;
#pragma unroll
      for (int j = 6; j < 12; ++j) { pref[j] = s; s += cnt[j]; }
    }
    {
      int s = 768;
#pragma unroll
      for (int j = 12; j < 16; ++j) { pref[j] = s; s += cnt[j]; }
    }
    const int c0 = pref[5] + cnt[5];          // panel 0 count (k < 384)
    const int c1 = pref[11] + cnt[11] - 384;  // panel 1 count
    const int c2 = pref[15] + cnt[15] - 768;  // panel 2 count

    // ---- build full active list: wave wv materializes chunks 2wv, 2wv+1 ----
#pragma unroll
    for (int jj = 0; jj < 2; ++jj) {
      const int j = wv * 2 + jj;
      const unsigned long long bits = mk[j];
      if ((bits >> lane) & 1ull) {
        const int below = __builtin_amdgcn_mbcnt_hi(
            (uint32_t)(bits >> 32),
            __builtin_amdgcn_mbcnt_lo((uint32_t)bits, 0));
        lst[pref[j] + below] = (uint16_t)(j * 64 + lane);
      }
    }
    // sentinel padding to x32 per panel (k=NN -> zeroed row, +0.0f exact)
    if (tid < 96) {
      const int p = tid >> 5, jn = tid & 31;
      const int c = (p == 0) ? c0 : ((p == 1) ? c1 : c2);
      if (c + jn < ((c + 31) & ~31)) lst[p * 384 + c + jn] = (uint16_t)NN;
    }
    __syncthreads();  // SYNC_C: lst complete

    // ---- recurrent term: (P0 + P1) + P2, sequential k within panels ----
    float P0, P1, P2;
    if (w_bf) {
      P0 = gB(0, (c0 + 31) & ~31);
      P1 = gB(384, (c1 + 31) & ~31);
      P2 = gB(768, (c2 + 31) & ~31);
    } else {
      P0 = gF(0, c0);
      P1 = gF(384, 384 + c1);
      P2 = gF(768, 768 + c2);
    }
    const float a = (P0 + P1) + P2;

    // ---- LIF update, reference op order, f32 ----
    const float xv = (xx + a) + bz;
    v = (y ? 0.0f : 0.5f * v) + xv;
    y = (v > 0.5f);

    __builtin_nontemporal_store(y ? 1.0f : 0.0f, &out[off]);
    // No end-of-step barrier needed: lst(t+1) writes happen after
    // SYNC_B(t+1); gather(t) LDS reads complete before SYNC_A(t+1).
  }
}

// ---------------------------------------------------------------------------
// Kernel 1b (fallback, R10-verified): per-sample LIF, 128 blocks x 1024 thr.
// Used only if ws_size cannot hold the mask exchange buffers.
// ---------------------------------------------------------------------------
__global__ __launch_bounds__(1024) void lif_persample(
    const void* __restrict__ tx_raw, const float* __restrict__ bias,
    const float* __restrict__ WtF32, const uint16_t* __restrict__ WtBf,
    const uint32_t* __restrict__ dirty, float* __restrict__ out) {
  const int b = blockIdx.x;
  const int tid = threadIdx.x;
  const int lane = tid & 63;
  const int wv = tid >> 6;

  __shared__ uint16_t lst[NN] __attribute__((aligned(16)));
  __shared__ int wcnt[16];
  __shared__ int sprobe;

  if (tid == 0) sprobe = 0;
  __syncthreads();
  {
    const uint32_t* txw = (const uint32_t*)tx_raw;
    int local = 0;
#pragma unroll
    for (int i = 0; i < 2; ++i) {
      const uint32_t f = (txw[tid * 2 + i] >> 7) & 0xFFu;
      local += (f >= 0x74u && f < 0x81u) ? 1 : 0;
    }
    atomicAdd(&sprobe, local);
  }
  __syncthreads();
  const bool tx_is_bf16 = (sprobe > 1024);
  const bool w_bf = (*dirty == 0u);

  const uint16_t* __restrict__ txh = (const uint16_t*)tx_raw;
  const float* __restrict__ txf = (const float*)tx_raw;
  const float bz = bias[tid];

  const int pidx = (wv < 6) ? 0 : ((wv < 12) ? 1 : 2);
  const int pw0 = (pidx == 0) ? 0 : ((pidx == 1) ? 6 : 12);

  const uint16_t* __restrict__ rowB = WtBf + tid;
  const float* __restrict__ rowF = WtF32 + tid;

  float v = 0.0f;
  int y = 0;

  auto gB = [&](int pbase, int cnt) -> float {
    float acc = 0.0f;
    for (int i = 0; i < cnt; i += 32) {
      const ushort8* lp = (const ushort8*)(lst + pbase + i);
      const ushort8 a0 = lp[0];
      const ushort8 a1 = lp[1];
      const ushort8 a2 = lp[2];
      const ushort8 a3 = lp[3];
      float wbuf[32];
#pragma unroll
      for (int u = 0; u < 8; ++u) {
        const int k = __builtin_amdgcn_readfirstlane((int)a0[u]);
        wbuf[u] = bfbits2f((uint32_t)rowB[k << 10]);
      }
#pragma unroll
      for (int u = 0; u < 8; ++u) {
        const int k = __builtin_amdgcn_readfirstlane((int)a1[u]);
        wbuf[8 + u] = bfbits2f((uint32_t)rowB[k << 10]);
      }
#pragma unroll
      for (int u = 0; u < 8; ++u) {
        const int k = __builtin_amdgcn_readfirstlane((int)a2[u]);
        wbuf[16 + u] = bfbits2f((uint32_t)rowB[k << 10]);
      }
#pragma unroll
      for (int u = 0; u < 8; ++u) {
        const int k = __builtin_amdgcn_readfirstlane((int)a3[u]);
        wbuf[24 + u] = bfbits2f((uint32_t)rowB[k << 10]);
      }
#pragma unroll
      for (int u = 0; u < 32; ++u) acc += wbuf[u];
    }
    return acc;
  };

  auto gF = [&](int s, int e) -> float {
    float acc = 0.0f;
    int i = s;
    for (; i + 8 <= e; i += 8) {
      float w[8];
#pragma unroll
      for (int u = 0; u < 8; ++u) {
        const int k = __builtin_amdgcn_readfirstlane((int)lst[i + u]);
        w[u] = rowF[k << 10];
      }
#pragma unroll
      for (int u = 0; u < 8; ++u) acc += w[u];
    }
    for (; i < e; ++i) {
      const int k = __builtin_amdgcn_readfirstlane((int)lst[i]);
      acc += rowF[k << 10];
    }
    return acc;
  };

  for (int t = 0; t < TT; ++t) {
    const unsigned long long m = __ballot(y);
    if (lane == 0) wcnt[wv] = __popcll(m);
    __syncthreads();
    int base = 0, c0 = 0, c1 = 0, c2 = 0;
#pragma unroll
    for (int w = 0; w < 16; ++w) {
      const int c = wcnt[w];
      c0 += (w < 6) ? c : 0;
      c1 += (w >= 6 && w < 12) ? c : 0;
      c2 += (w >= 12) ? c : 0;
      base += (w >= pw0 && w < wv) ? c : 0;
    }
    if (y) {
      const int below = __builtin_amdgcn_mbcnt_hi(
          (uint32_t)(m >> 32), __builtin_amdgcn_mbcnt_lo((uint32_t)m, 0));
      lst[pidx * 384 + base + below] = (uint16_t)tid;
    }
    if (tid < 96) {
      const int p = tid >> 5, jn = tid & 31;
      const int c = (p == 0) ? c0 : ((p == 1) ? c1 : c2);
      if (c + jn < ((c + 31) & ~31)) lst[p * 384 + c + jn] = (uint16_t)NN;
    }
    __syncthreads();

    float P0, P1, P2;
    if (w_bf) {
      P0 = gB(0, (c0 + 31) & ~31);
      P1 = gB(384, (c1 + 31) & ~31);
      P2 = gB(768, (c2 + 31) & ~31);
    } else {
      P0 = gF(0, c0);
      P1 = gF(384, 384 + c1);
      P2 = gF(768, 768 + c2);
    }
    const float a = (P0 + P1) + P2;

    const int off = (t * BB + b) * NN + tid;
    const float xx = tx_is_bf16
        ? bfbits2f((uint32_t)__builtin_nontemporal_load(&txh[off]))
        : __builtin_nontemporal_load(&txf[off]);
    const float xv = (xx + a) + bz;
    v = (y ? 0.0f : 0.5f * v) + xv;
    y = (v > 0.5f);

    __builtin_nontemporal_store(y ? 1.0f : 0.0f, &out[off]);
  }
}

extern "C" void kernel_launch(void* const* d_in, const int* in_sizes, int n_in,
                              void* d_out, int out_size, void* d_ws, size_t ws_size,
                              hipStream_t stream) {
  // Inputs by element count: tx = 128*128*1024 (bf16-packed),
  // W = 1024*1024 (f32, bf16-valued), b = 1024 (f32).
  const void* tx = nullptr;
  float* W = nullptr;
  const float* bs = nullptr;
  for (int i = 0; i < n_in; ++i) {
    if (in_sizes[i] == TT * BB * NN) tx = d_in[i];
    else if (in_sizes[i] == NN * NN) W = (float*)d_in[i];
    else if (in_sizes[i] == NN) bs = (const float*)d_in[i];
  }
  float* out = (float*)d_out;                     // [T, B, N] f32 spikes

  // Workspace layout:
  //   [0, 2MB)                bf16 W^T (1024 rows)
  //   [2MB, 2MB+2KB)          zero row (sentinel k=1024)
  //   @2MB+2048               dirty flag (u32)
  //   @2MB+4096               gmask: u64[256 blocks][4 slots][16 cells] = 128KB
  const size_t MB2 = 2u * 1024u * 1024u;
  uint16_t* WtBf = (uint16_t*)d_ws;
  uint16_t* zrow = WtBf + NN * NN;                // row index 1024
  uint32_t* dirty = (uint32_t*)((char*)d_ws + MB2 + 2048u);
  unsigned long long* gmask =
      (unsigned long long*)((char*)d_ws + MB2 + 4096u);
  const size_t GMASK_BYTES = 256u * 4u * 16u * 8u;  // 131072
  const size_t need = MB2 + 4096u + GMASK_BYTES;

  // ws is poisoned 0xAA each launch — clear dirty flag, sentinel row, cells.
  hipMemsetAsync(dirty, 0, sizeof(uint32_t), stream);
  hipMemsetAsync(zrow, 0, NN * sizeof(uint16_t), stream);

  w_transpose_repack<<<dim3(528), dim3(256), 0, stream>>>(W, WtBf, dirty);

  if (ws_size >= need) {
    hipMemsetAsync(gmask, 0, GMASK_BYTES, stream);
    lif_half<<<dim3(256), dim3(512), 0, stream>>>(tx, bs, W, WtBf, dirty,
                                                  gmask, out);
  } else {
    lif_persample<<<dim3(BB), dim3(1024), 0, stream>>>(tx, bs, W, WtBf, dirty,
                                                       out);
  }
}